// Round 21
// baseline (466.383 us; speedup 1.0000x reference)
//
#include <hip/hip_runtime.h>

typedef float f32x4 __attribute__((ext_vector_type(4)));
typedef short short8 __attribute__((ext_vector_type(8)));
typedef short s16x4 __attribute__((ext_vector_type(4)));

#define B_TOT   8192
#define T_STEPS 256
#define D_INP   17
#define OUT0 ((long)B_TOT * T_STEPS * D_INP)
#define L2E 1.4426950408889634f

__device__ __forceinline__ float bf2f(unsigned short u) {
    union { unsigned int i; float f; } v; v.i = ((unsigned int)u) << 16; return v.f;
}
__device__ __forceinline__ unsigned short f2bf(float x) {
    union { float f; unsigned int i; } v; v.f = x;
    unsigned int r = (v.i + 0x7fffu + ((v.i >> 16) & 1u)) >> 16;
    return (unsigned short)r;
}
__device__ __forceinline__ short f2bfs(float x) { return (short)f2bf(x); }

__device__ __forceinline__ float fsig(float x) {
    float t = __builtin_amdgcn_exp2f(-1.4426950408889634f * x);
    return __builtin_amdgcn_rcpf(1.0f + t);
}
__device__ __forceinline__ float ftanh(float x) {
    float t = __builtin_amdgcn_exp2f(-2.8853900817779268f * x);
    return 2.0f * __builtin_amdgcn_rcpf(1.0f + t) - 1.0f;
}

// VALU-pipe exp2: floor + degree-6 Taylor Horner + ldexp. ~10 VALU ops,
// rel err ~1.5e-5 (better than needed). Offloads the quarter-rate trans pipe.
__device__ __forceinline__ float exp2poly(float y) {
    const float fl = floorf(y);
    const float f  = y - fl;
    float p = 1.5403530e-4f;               // ln2^6/720
    p = fmaf(p, f, 1.3333558e-3f);         // ln2^5/120
    p = fmaf(p, f, 9.6181291e-3f);         // ln2^4/24
    p = fmaf(p, f, 5.5504109e-2f);         // ln2^3/6
    p = fmaf(p, f, 2.4022651e-1f);         // ln2^2/2
    p = fmaf(p, f, 6.9314718e-1f);         // ln2
    p = fmaf(p, f, 1.0f);
    return ldexpf(p, (int)fl);
}

// pack two f32 -> one dword of 2 bf16 (RNE), single VALU op
__device__ __forceinline__ unsigned cvtpk(float lo, float hi) {
    unsigned r;
    asm("v_cvt_pk_bf16_f32 %0, %1, %2" : "=v"(r) : "v"(lo), "v"(hi));
    return r;
}

union U2S8 { uint4 u; short8 s; };
union U1S4 { uint2 u; s16x4 s; };

#if __has_builtin(__builtin_amdgcn_mfma_f32_16x16x16bf16_1k)
__device__ __forceinline__ f32x4 mfma16(s16x4 a, s16x4 b, f32x4 c) {
    return __builtin_amdgcn_mfma_f32_16x16x16bf16_1k(a, b, c, 0, 0, 0);
}
#else
__device__ __forceinline__ f32x4 mfma16(s16x4 a, s16x4 b, f32x4 c) {
    f32x4 d;
    asm volatile("v_mfma_f32_16x16x16_bf16 %0, %1, %2, %3\n\t"
                 "s_nop 7\n\ts_nop 7"
                 : "=v"(d) : "v"(a), "v"(b), "v"(c));
    return d;
}
#endif

// cn via shared-denominator with POLY exps (VALU pipe);
// h via fsig*ftanh (HW trans: 2 exp + 2 rcp) — validated r17 form.
// Trans-pipe instrs/cell: 8 -> 5 (1 rcp + h's 2 exp + 2 rcp).
__device__ __forceinline__ float cell_cnshared(float gi, float gf, float gg, float go,
                                               float& c) {
    const float Ei = exp2poly(-L2E * gi);
    const float Ef = exp2poly(-L2E * gf);
    const float Eg = exp2poly(-2.f * L2E * gg);
    const float pf = 1.f + Ef;
    const float A  = (1.f + Ei) * (1.f + Eg);
    const float cn = (c * A + pf * (1.f - Eg)) * __builtin_amdgcn_rcpf(pf * A);
    c = cn;
    return fsig(go) * ftanh(cn);
}

// Single wave per 16-row batch tile.
// Encoder: permuted gate rows => lane's C/D IS its next-step B-fragment (K=32);
//          x-part MFMAs rotated one step ahead (xacc).
// Decoder: 17 units via K=16 MFMAs (direct layout); unit-16 gate rows
//          replicated (local h16, no cross-lane ops).
__global__ __launch_bounds__(64, 1)
void lstm_ae_mfma13(const float* __restrict__ x,
                    const float* __restrict__ wih_e,
                    const float* __restrict__ whh_e,
                    const float* __restrict__ bih_e,
                    const float* __restrict__ bhh_e,
                    const float* __restrict__ w_encfc,
                    const float* __restrict__ b_encfc,
                    const float* __restrict__ w_decfc,
                    const float* __restrict__ b_decfc,
                    const float* __restrict__ wih_d,
                    const float* __restrict__ whh_d,
                    const float* __restrict__ bih_d,
                    const float* __restrict__ bhh_d,
                    float* __restrict__ out)
{
    const int lane = threadIdx.x;
    const int n    = lane & 15;    // batch row (B-col / C-col); also A-row idx
    const int G    = lane >> 4;    // k-group / C-row group
    const int row0 = blockIdx.x * 16;

    __shared__ float hfin[16][33];
    __shared__ float zbuf[16][8];

    // ---------------- encoder fragments, permuted gate rows ----------------
    short8 Aih[4][2], Awh[4][2];
    f32x4  biasE[4][2];
#pragma unroll
    for (int q = 0; q < 4; ++q) {
#pragma unroll
        for (int j = 0; j < 2; ++j) {
            const int u0   = 8*(n>>2) + 4*j + (n&3);   // A-row unit for this lane
            const int grow = 32*q + u0;
#pragma unroll
            for (int e = 0; e < 8; ++e) {
                const int k = 8*G + e;
                Awh[q][j][e] = f2bfs(whh_e[grow*32 + k]);
                Aih[q][j][e] = (k < D_INP) ? f2bfs(wih_e[grow*D_INP + k]) : (short)0;
            }
#pragma unroll
            for (int r = 0; r < 4; ++r) {
                const int u = 8*G + 4*j + r;           // C-slot unit
                biasE[q][j][r] = bih_e[32*q + u] + bhh_e[32*q + u];
            }
        }
    }

    float c[8], hreg[8];
#pragma unroll
    for (int e = 0; e < 8; ++e) { c[e] = 0.f; hreg[e] = 0.f; }
    short8 bh;
#pragma unroll
    for (int e = 0; e < 8; ++e) bh[e] = 0;

    const long xrow = (long)(row0 + n) * (T_STEPS * D_INP);

    // depth-2 x prefetch
    float xv[8], xn1[8];
#pragma unroll
    for (int e = 0; e < 8; ++e) {
        const int k = 8*G + e;
        xv[e]  = (k < D_INP) ? x[xrow + k] : 0.f;
        xn1[e] = (k < D_INP) ? x[xrow + D_INP + k] : 0.f;
    }

    // xacc(t=0) = bias + Wih x0
    f32x4 xacc[4][2];
    {
        U2S8 bx0;
        bx0.u = make_uint4(cvtpk(xv[0], xv[1]), cvtpk(xv[2], xv[3]),
                           cvtpk(xv[4], xv[5]), cvtpk(xv[6], xv[7]));
#pragma unroll
        for (int q = 0; q < 4; ++q)
#pragma unroll
            for (int j = 0; j < 2; ++j)
                xacc[q][j] = __builtin_amdgcn_mfma_f32_16x16x32_bf16(Aih[q][j], bx0.s, biasE[q][j], 0, 0, 0);
    }

    // ---------------- encoder loop (no LDS, no barriers) ----------------
    for (int t = 0; t < T_STEPS; ++t) {
        const int t2 = (t+2 < T_STEPS) ? (t+2) : (T_STEPS-1);
        float xn2[8];
#pragma unroll
        for (int e = 0; e < 8; ++e) {
            const int k = 8*G + e;
            xn2[e] = (k < D_INP) ? x[xrow + (long)t2*D_INP + k] : 0.f;
        }

        // critical chain: h-MFMA (C = xacc) -> cell -> pack bh
        f32x4 a[4][2];
#pragma unroll
        for (int q = 0; q < 4; ++q)
#pragma unroll
            for (int j = 0; j < 2; ++j)
                a[q][j] = __builtin_amdgcn_mfma_f32_16x16x32_bf16(Awh[q][j], bh, xacc[q][j], 0, 0, 0);

#pragma unroll
        for (int j = 0; j < 2; ++j)
#pragma unroll
            for (int r = 0; r < 4; ++r) {
                const int e = 4*j + r;
                hreg[e] = cell_cnshared(a[0][j][r], a[1][j][r], a[2][j][r], a[3][j][r], c[e]);
            }

        U2S8 bhu;
        bhu.u = make_uint4(cvtpk(hreg[0], hreg[1]), cvtpk(hreg[2], hreg[3]),
                           cvtpk(hreg[4], hreg[5]), cvtpk(hreg[6], hreg[7]));
        bh = bhu.s;

        // next-step x part (independent; issues in the cell's shadow)
        U2S8 bxn;
        bxn.u = make_uint4(cvtpk(xn1[0], xn1[1]), cvtpk(xn1[2], xn1[3]),
                           cvtpk(xn1[4], xn1[5]), cvtpk(xn1[6], xn1[7]));
#pragma unroll
        for (int q = 0; q < 4; ++q)
#pragma unroll
            for (int j = 0; j < 2; ++j)
                xacc[q][j] = __builtin_amdgcn_mfma_f32_16x16x32_bf16(Aih[q][j], bxn.s, biasE[q][j], 0, 0, 0);

#pragma unroll
        for (int e = 0; e < 8; ++e) { xv[e] = xn1[e]; xn1[e] = xn2[e]; }
    }

    // ---------------- enc_fc -> z -> dec_fc (one-time glue) ----------------
#pragma unroll
    for (int j = 0; j < 2; ++j)
#pragma unroll
        for (int r = 0; r < 4; ++r)
            hfin[n][8*G + 4*j + r] = hreg[4*j + r];
    __syncthreads();

#pragma unroll
    for (int ti = 0; ti < 2; ++ti) {
        const int tk = lane*2 + ti;
        const int nn = tk >> 3;
        const int p  = tk & 7;
        float s = b_encfc[p];
#pragma unroll
        for (int jj = 0; jj < 32; ++jj)
            s += hfin[nn][jj] * w_encfc[p*32 + jj];
        out[OUT0 + (long)(row0+nn)*8 + p] = s;
        zbuf[nn][p] = s;
    }
    __syncthreads();

    // dec_in B-fragment per lane (hi+mid split, one-time), K=32 layout k=8G+e
    short8 bdvH, bdvM;
#pragma unroll
    for (int e = 0; e < 8; ++e) {
        const int k = 8*G + e;
        float v = b_decfc[k];
#pragma unroll
        for (int p = 0; p < 8; ++p)
            v += zbuf[n][p] * w_decfc[k*8 + p];
        const unsigned short hh = f2bf(v);
        bdvH[e] = (short)hh;
        bdvM[e] = f2bfs(v - bf2f(hh));
    }

    // ---------------- decoder fragments: direct layout, units 0..15 + unit16 ----------------
    s16x4  AwhD16[4];      // whh K=16 fragment: A-row = n (unit), k = 4G+e
    s16x4  Awh16;          // unit-16: REPLICATED gate rows (row n -> gate n&3)
    f32x4  accd[4];        // const x-part + bias, C-slot u = 4G+r
    f32x4  accd16;         // unit-16 gates const (all lanes, gate r in slot r)
    float  w16colv[4][4];  // rank-1: [q][r] = whh_d[(q*17 + 4G+r)*17 + 16]
    float  w1616v[4];      // [r] = whh_d[(r*17+16)*17 + 16]
    {
#pragma unroll
        for (int q = 0; q < 4; ++q) {
#pragma unroll
            for (int e = 0; e < 4; ++e) {
                const int k = 4*G + e;
                AwhD16[q][e] = f2bfs(whh_d[(q*17 + n)*17 + k]);
            }
#pragma unroll
            for (int r = 0; r < 4; ++r)
                w16colv[q][r] = whh_d[(q*17 + 4*G + r)*17 + 16];
        }
        {
            const int gq = n & 3;              // replicated gate for this A-row
#pragma unroll
            for (int e = 0; e < 4; ++e) {
                const int k = 4*G + e;
                Awh16[e] = f2bfs(whh_d[(gq*17 + 16)*17 + k]);
            }
        }
#pragma unroll
        for (int r = 0; r < 4; ++r)
            w1616v[r] = whh_d[(r*17 + 16)*17 + 16];

        // accd: 4 MFMAs K=32 (direct A rows = unit n), hi+mid split on dec_in
#pragma unroll
        for (int q = 0; q < 4; ++q) {
            short8 ADH, ADM;
#pragma unroll
            for (int e = 0; e < 8; ++e) {
                const int k = 8*G + e;
                const float iv = wih_d[(q*17 + n)*32 + k];
                const short hi = f2bfs(iv);
                ADH[e] = hi;
                ADM[e] = f2bfs(iv - bf2f((unsigned short)hi));
            }
            f32x4 acc0;
#pragma unroll
            for (int r = 0; r < 4; ++r) {
                const int u = 4*G + r;
                acc0[r] = bih_d[q*17 + u] + bhh_d[q*17 + u];
            }
            acc0 = __builtin_amdgcn_mfma_f32_16x16x32_bf16(ADH, bdvH, acc0, 0, 0, 0);
            acc0 = __builtin_amdgcn_mfma_f32_16x16x32_bf16(ADM, bdvH, acc0, 0, 0, 0);
            acc0 = __builtin_amdgcn_mfma_f32_16x16x32_bf16(ADH, bdvM, acc0, 0, 0, 0);
            accd[q] = acc0;
        }
        // unit-16 const gates: REPLICATED rows (row n -> gate n&3)
        {
            const int gq = n & 3;
            short8 A16H, A16M;
#pragma unroll
            for (int e = 0; e < 8; ++e) {
                const int k = 8*G + e;
                const float iv = wih_d[(gq*17 + 16)*32 + k];
                const short hi = f2bfs(iv);
                A16H[e] = hi;
                A16M[e] = f2bfs(iv - bf2f((unsigned short)hi));
            }
            f32x4 acc0;
#pragma unroll
            for (int r = 0; r < 4; ++r)
                acc0[r] = bih_d[r*17 + 16] + bhh_d[r*17 + 16];
            acc0 = __builtin_amdgcn_mfma_f32_16x16x32_bf16(A16H, bdvH, acc0, 0, 0, 0);
            acc0 = __builtin_amdgcn_mfma_f32_16x16x32_bf16(A16M, bdvH, acc0, 0, 0, 0);
            acc0 = __builtin_amdgcn_mfma_f32_16x16x32_bf16(A16H, bdvM, acc0, 0, 0, 0);
            accd16 = acc0;
        }
    }

    float cd[4];
#pragma unroll
    for (int r = 0; r < 4; ++r) cd[r] = 0.f;
    float c16 = 0.f, h16b = 0.f;
    s16x4 bh4;
#pragma unroll
    for (int e = 0; e < 4; ++e) bh4[e] = 0;

    const long orow = (long)(row0 + n) * (T_STEPS * D_INP);

    // ---------------- decoder loop (no barriers, no cross-lane ops) ----------------
    for (int t = 0; t < T_STEPS; ++t) {
        f32x4 d[4];
#pragma unroll
        for (int q = 0; q < 4; ++q)
            d[q] = mfma16(AwhD16[q], bh4, accd[q]);
        f32x4 a16 = mfma16(Awh16, bh4, accd16);

        // rank-1: k=16 column x h16(t-1)  (f32, exact)
#pragma unroll
        for (int q = 0; q < 4; ++q)
#pragma unroll
            for (int r = 0; r < 4; ++r)
                d[q][r] += w16colv[q][r] * h16b;
#pragma unroll
        for (int r = 0; r < 4; ++r)
            a16[r] += w1616v[r] * h16b;

        float hval[4];
#pragma unroll
        for (int r = 0; r < 4; ++r)
            hval[r] = cell_cnshared(d[0][r], d[1][r], d[2][r], d[3][r], cd[r]);

        // pack bh4 EARLY (feeds next step's MFMAs)
        U1S4 p;
        p.u = make_uint2(cvtpk(hval[0], hval[1]), cvtpk(hval[2], hval[3]));
        bh4 = p.s;

        // unit 16: every lane holds all 4 gates (slots r) -> local h16
        const float h16 = cell_cnshared(a16[0], a16[1], a16[2], a16[3], c16);
        h16b = h16;

        const long ob = orow + (long)t * D_INP;
#pragma unroll
        for (int r = 0; r < 4; ++r)
            out[ob + 4*G + r] = hval[r];
        if (G == 0)
            out[ob + 16] = h16;
    }
}

extern "C" void kernel_launch(void* const* d_in, const int* in_sizes, int n_in,
                              void* d_out, int out_size, void* d_ws, size_t ws_size,
                              hipStream_t stream) {
    (void)in_sizes; (void)n_in; (void)d_ws; (void)ws_size; (void)out_size;
    dim3 grid(B_TOT / 16);
    dim3 block(64);
    hipLaunchKernelGGL(lstm_ae_mfma13, grid, block, 0, stream,
        (const float*)d_in[0],
        (const float*)d_in[1],
        (const float*)d_in[2],
        (const float*)d_in[3],
        (const float*)d_in[4],
        (const float*)d_in[5],
        (const float*)d_in[6],
        (const float*)d_in[7],
        (const float*)d_in[8],
        (const float*)d_in[9],
        (const float*)d_in[10],
        (const float*)d_in[11],
        (const float*)d_in[12],
        (float*)d_out);
}

// Round 22
// 332.255 us; speedup vs baseline: 1.4037x; 1.4037x over previous
//
#include <hip/hip_runtime.h>

typedef float f32x4 __attribute__((ext_vector_type(4)));
typedef short short8 __attribute__((ext_vector_type(8)));
typedef short s16x4 __attribute__((ext_vector_type(4)));

#define B_TOT   8192
#define T_STEPS 256
#define D_INP   17
#define OUT0 ((long)B_TOT * T_STEPS * D_INP)
#define L2E 1.4426950408889634f

__device__ __forceinline__ float bf2f(unsigned short u) {
    union { unsigned int i; float f; } v; v.i = ((unsigned int)u) << 16; return v.f;
}
__device__ __forceinline__ unsigned short f2bf(float x) {
    union { float f; unsigned int i; } v; v.f = x;
    unsigned int r = (v.i + 0x7fffu + ((v.i >> 16) & 1u)) >> 16;
    return (unsigned short)r;
}
__device__ __forceinline__ short f2bfs(float x) { return (short)f2bf(x); }

__device__ __forceinline__ float fsig(float x) {
    float t = __builtin_amdgcn_exp2f(-1.4426950408889634f * x);
    return __builtin_amdgcn_rcpf(1.0f + t);
}
__device__ __forceinline__ float ftanh(float x) {
    float t = __builtin_amdgcn_exp2f(-2.8853900817779268f * x);
    return 2.0f * __builtin_amdgcn_rcpf(1.0f + t) - 1.0f;
}

// pack two f32 -> one dword of 2 bf16 (RNE), single VALU op
__device__ __forceinline__ unsigned cvtpk(float lo, float hi) {
    unsigned r;
    asm("v_cvt_pk_bf16_f32 %0, %1, %2" : "=v"(r) : "v"(lo), "v"(hi));
    return r;
}

union U2S8 { uint4 u; short8 s; };
union U1S4 { uint2 u; s16x4 s; };

#if __has_builtin(__builtin_amdgcn_mfma_f32_16x16x16bf16_1k)
__device__ __forceinline__ f32x4 mfma16(s16x4 a, s16x4 b, f32x4 c) {
    return __builtin_amdgcn_mfma_f32_16x16x16bf16_1k(a, b, c, 0, 0, 0);
}
#else
__device__ __forceinline__ f32x4 mfma16(s16x4 a, s16x4 b, f32x4 c) {
    f32x4 d;
    asm volatile("v_mfma_f32_16x16x16_bf16 %0, %1, %2, %3\n\t"
                 "s_nop 7\n\ts_nop 7"
                 : "=v"(d) : "v"(a), "v"(b), "v"(c));
    return d;
}
#endif

// Validated (r17): cn via shared-denominator (3 exp + 1 rcp),
// h via fsig*ftanh (2 exp + 2 rcp). 8 trans/unit vs 10 naive.
__device__ __forceinline__ float cell_cnshared(float gi, float gf, float gg, float go,
                                               float& c) {
    const float Ei = __builtin_amdgcn_exp2f(-L2E * gi);
    const float Ef = __builtin_amdgcn_exp2f(-L2E * gf);
    const float Eg = __builtin_amdgcn_exp2f(-2.f * L2E * gg);
    const float pf = 1.f + Ef;
    const float A  = (1.f + Ei) * (1.f + Eg);
    const float cn = (c * A + pf * (1.f - Eg)) * __builtin_amdgcn_rcpf(pf * A);
    c = cn;
    return fsig(go) * ftanh(cn);
}

// Single wave per 16-row batch tile.
// Encoder: permuted gate rows => lane's C/D IS its next-step B-fragment (K=32);
//          x-part MFMAs rotated one step ahead (xacc) off the critical chain.
// Decoder: 17 units via K=16 MFMAs (direct layout); unit 16 gate rows
//          REPLICATED (row n -> gate n&3) so every lane computes h16 locally
//          (no cross-lane op).
__global__ __launch_bounds__(64, 1)
void lstm_ae_mfma11(const float* __restrict__ x,
                    const float* __restrict__ wih_e,
                    const float* __restrict__ whh_e,
                    const float* __restrict__ bih_e,
                    const float* __restrict__ bhh_e,
                    const float* __restrict__ w_encfc,
                    const float* __restrict__ b_encfc,
                    const float* __restrict__ w_decfc,
                    const float* __restrict__ b_decfc,
                    const float* __restrict__ wih_d,
                    const float* __restrict__ whh_d,
                    const float* __restrict__ bih_d,
                    const float* __restrict__ bhh_d,
                    float* __restrict__ out)
{
    const int lane = threadIdx.x;
    const int n    = lane & 15;    // batch row (B-col / C-col); also A-row idx
    const int G    = lane >> 4;    // k-group / C-row group
    const int row0 = blockIdx.x * 16;

    __shared__ float hfin[16][33];
    __shared__ float zbuf[16][8];

    // ---------------- encoder fragments, permuted gate rows ----------------
    short8 Aih[4][2], Awh[4][2];
    f32x4  biasE[4][2];
#pragma unroll
    for (int q = 0; q < 4; ++q) {
#pragma unroll
        for (int j = 0; j < 2; ++j) {
            const int u0   = 8*(n>>2) + 4*j + (n&3);   // A-row unit for this lane
            const int grow = 32*q + u0;
#pragma unroll
            for (int e = 0; e < 8; ++e) {
                const int k = 8*G + e;
                Awh[q][j][e] = f2bfs(whh_e[grow*32 + k]);
                Aih[q][j][e] = (k < D_INP) ? f2bfs(wih_e[grow*D_INP + k]) : (short)0;
            }
#pragma unroll
            for (int r = 0; r < 4; ++r) {
                const int u = 8*G + 4*j + r;           // C-slot unit
                biasE[q][j][r] = bih_e[32*q + u] + bhh_e[32*q + u];
            }
        }
    }

    float c[8], hreg[8];
#pragma unroll
    for (int e = 0; e < 8; ++e) { c[e] = 0.f; hreg[e] = 0.f; }
    short8 bh;
#pragma unroll
    for (int e = 0; e < 8; ++e) bh[e] = 0;

    const long xrow = (long)(row0 + n) * (T_STEPS * D_INP);

    // depth-2 x prefetch
    float xv[8], xn1[8];
#pragma unroll
    for (int e = 0; e < 8; ++e) {
        const int k = 8*G + e;
        xv[e]  = (k < D_INP) ? x[xrow + k] : 0.f;
        xn1[e] = (k < D_INP) ? x[xrow + D_INP + k] : 0.f;
    }

    // xacc(t=0) = bias + Wih x0
    f32x4 xacc[4][2];
    {
        U2S8 bx0;
        bx0.u = make_uint4(cvtpk(xv[0], xv[1]), cvtpk(xv[2], xv[3]),
                           cvtpk(xv[4], xv[5]), cvtpk(xv[6], xv[7]));
#pragma unroll
        for (int q = 0; q < 4; ++q)
#pragma unroll
            for (int j = 0; j < 2; ++j)
                xacc[q][j] = __builtin_amdgcn_mfma_f32_16x16x32_bf16(Aih[q][j], bx0.s, biasE[q][j], 0, 0, 0);
    }

    // ---------------- encoder loop (no LDS, no barriers) ----------------
    for (int t = 0; t < T_STEPS; ++t) {
        const int t2 = (t+2 < T_STEPS) ? (t+2) : (T_STEPS-1);
        float xn2[8];
#pragma unroll
        for (int e = 0; e < 8; ++e) {
            const int k = 8*G + e;
            xn2[e] = (k < D_INP) ? x[xrow + (long)t2*D_INP + k] : 0.f;
        }

        // critical chain: h-MFMA (C = xacc) -> cell -> pack bh
        f32x4 a[4][2];
#pragma unroll
        for (int q = 0; q < 4; ++q)
#pragma unroll
            for (int j = 0; j < 2; ++j)
                a[q][j] = __builtin_amdgcn_mfma_f32_16x16x32_bf16(Awh[q][j], bh, xacc[q][j], 0, 0, 0);

#pragma unroll
        for (int j = 0; j < 2; ++j)
#pragma unroll
            for (int r = 0; r < 4; ++r) {
                const int e = 4*j + r;
                hreg[e] = cell_cnshared(a[0][j][r], a[1][j][r], a[2][j][r], a[3][j][r], c[e]);
            }

        U2S8 bhu;
        bhu.u = make_uint4(cvtpk(hreg[0], hreg[1]), cvtpk(hreg[2], hreg[3]),
                           cvtpk(hreg[4], hreg[5]), cvtpk(hreg[6], hreg[7]));
        bh = bhu.s;

        // next-step x part (independent; issues in the cell's shadow)
        U2S8 bxn;
        bxn.u = make_uint4(cvtpk(xn1[0], xn1[1]), cvtpk(xn1[2], xn1[3]),
                           cvtpk(xn1[4], xn1[5]), cvtpk(xn1[6], xn1[7]));
#pragma unroll
        for (int q = 0; q < 4; ++q)
#pragma unroll
            for (int j = 0; j < 2; ++j)
                xacc[q][j] = __builtin_amdgcn_mfma_f32_16x16x32_bf16(Aih[q][j], bxn.s, biasE[q][j], 0, 0, 0);

#pragma unroll
        for (int e = 0; e < 8; ++e) { xv[e] = xn1[e]; xn1[e] = xn2[e]; }
    }

    // ---------------- enc_fc -> z -> dec_fc (one-time glue) ----------------
#pragma unroll
    for (int j = 0; j < 2; ++j)
#pragma unroll
        for (int r = 0; r < 4; ++r)
            hfin[n][8*G + 4*j + r] = hreg[4*j + r];
    __syncthreads();

#pragma unroll
    for (int ti = 0; ti < 2; ++ti) {
        const int tk = lane*2 + ti;
        const int nn = tk >> 3;
        const int p  = tk & 7;
        float s = b_encfc[p];
#pragma unroll
        for (int jj = 0; jj < 32; ++jj)
            s += hfin[nn][jj] * w_encfc[p*32 + jj];
        out[OUT0 + (long)(row0+nn)*8 + p] = s;
        zbuf[nn][p] = s;
    }
    __syncthreads();

    // dec_in B-fragment per lane (hi+mid split, one-time), K=32 layout k=8G+e
    short8 bdvH, bdvM;
#pragma unroll
    for (int e = 0; e < 8; ++e) {
        const int k = 8*G + e;
        float v = b_decfc[k];
#pragma unroll
        for (int p = 0; p < 8; ++p)
            v += zbuf[n][p] * w_decfc[k*8 + p];
        const unsigned short hh = f2bf(v);
        bdvH[e] = (short)hh;
        bdvM[e] = f2bfs(v - bf2f(hh));
    }

    // ---------------- decoder fragments: direct layout, units 0..15 + unit16 ----------------
    s16x4  AwhD16[4];      // whh K=16 fragment: A-row = n (unit), k = 4G+e
    s16x4  Awh16;          // unit-16: REPLICATED gate rows (row n -> gate n&3)
    f32x4  accd[4];        // const x-part + bias, C-slot u = 4G+r
    f32x4  accd16;         // unit-16 gates const (all lanes, gate r in slot r)
    float  w16colv[4][4];  // rank-1: [q][r] = whh_d[(q*17 + 4G+r)*17 + 16]
    float  w1616v[4];      // [r] = whh_d[(r*17+16)*17 + 16]
    {
#pragma unroll
        for (int q = 0; q < 4; ++q) {
#pragma unroll
            for (int e = 0; e < 4; ++e) {
                const int k = 4*G + e;
                AwhD16[q][e] = f2bfs(whh_d[(q*17 + n)*17 + k]);
            }
#pragma unroll
            for (int r = 0; r < 4; ++r)
                w16colv[q][r] = whh_d[(q*17 + 4*G + r)*17 + 16];
        }
        {
            const int gq = n & 3;              // replicated gate for this A-row
#pragma unroll
            for (int e = 0; e < 4; ++e) {
                const int k = 4*G + e;
                Awh16[e] = f2bfs(whh_d[(gq*17 + 16)*17 + k]);
            }
        }
#pragma unroll
        for (int r = 0; r < 4; ++r)
            w1616v[r] = whh_d[(r*17 + 16)*17 + 16];

        // accd: 4 MFMAs K=32 (direct A rows = unit n), hi+mid split on dec_in
#pragma unroll
        for (int q = 0; q < 4; ++q) {
            short8 ADH, ADM;
#pragma unroll
            for (int e = 0; e < 8; ++e) {
                const int k = 8*G + e;
                const float iv = wih_d[(q*17 + n)*32 + k];
                const short hi = f2bfs(iv);
                ADH[e] = hi;
                ADM[e] = f2bfs(iv - bf2f((unsigned short)hi));
            }
            f32x4 acc0;
#pragma unroll
            for (int r = 0; r < 4; ++r) {
                const int u = 4*G + r;
                acc0[r] = bih_d[q*17 + u] + bhh_d[q*17 + u];
            }
            acc0 = __builtin_amdgcn_mfma_f32_16x16x32_bf16(ADH, bdvH, acc0, 0, 0, 0);
            acc0 = __builtin_amdgcn_mfma_f32_16x16x32_bf16(ADM, bdvH, acc0, 0, 0, 0);
            acc0 = __builtin_amdgcn_mfma_f32_16x16x32_bf16(ADH, bdvM, acc0, 0, 0, 0);
            accd[q] = acc0;
        }
        // unit-16 const gates: REPLICATED rows (row n -> gate n&3); every lane
        // ends with gate r of unit 16 (batch n) in C-slot r.
        {
            const int gq = n & 3;
            short8 A16H, A16M;
#pragma unroll
            for (int e = 0; e < 8; ++e) {
                const int k = 8*G + e;
                const float iv = wih_d[(gq*17 + 16)*32 + k];
                const short hi = f2bfs(iv);
                A16H[e] = hi;
                A16M[e] = f2bfs(iv - bf2f((unsigned short)hi));
            }
            f32x4 acc0;
#pragma unroll
            for (int r = 0; r < 4; ++r)
                acc0[r] = bih_d[r*17 + 16] + bhh_d[r*17 + 16];
            acc0 = __builtin_amdgcn_mfma_f32_16x16x32_bf16(A16H, bdvH, acc0, 0, 0, 0);
            acc0 = __builtin_amdgcn_mfma_f32_16x16x32_bf16(A16M, bdvH, acc0, 0, 0, 0);
            acc0 = __builtin_amdgcn_mfma_f32_16x16x32_bf16(A16H, bdvM, acc0, 0, 0, 0);
            accd16 = acc0;
        }
    }

    float cd[4];
#pragma unroll
    for (int r = 0; r < 4; ++r) cd[r] = 0.f;
    float c16 = 0.f, h16b = 0.f;
    s16x4 bh4;
#pragma unroll
    for (int e = 0; e < 4; ++e) bh4[e] = 0;

    const long orow = (long)(row0 + n) * (T_STEPS * D_INP);

    // ---------------- decoder loop (no barriers, no cross-lane ops) ----------------
    for (int t = 0; t < T_STEPS; ++t) {
        f32x4 d[4];
#pragma unroll
        for (int q = 0; q < 4; ++q)
            d[q] = mfma16(AwhD16[q], bh4, accd[q]);
        f32x4 a16 = mfma16(Awh16, bh4, accd16);

        // rank-1: k=16 column x h16(t-1)  (f32, exact)
#pragma unroll
        for (int q = 0; q < 4; ++q)
#pragma unroll
            for (int r = 0; r < 4; ++r)
                d[q][r] += w16colv[q][r] * h16b;
#pragma unroll
        for (int r = 0; r < 4; ++r)
            a16[r] += w1616v[r] * h16b;

        float hval[4];
#pragma unroll
        for (int r = 0; r < 4; ++r)
            hval[r] = cell_cnshared(d[0][r], d[1][r], d[2][r], d[3][r], cd[r]);

        // pack bh4 EARLY (feeds next step's MFMAs)
        U1S4 p;
        p.u = make_uint2(cvtpk(hval[0], hval[1]), cvtpk(hval[2], hval[3]));
        bh4 = p.s;

        // unit 16: every lane holds all 4 gates (slots r) -> local h16
        const float h16 = cell_cnshared(a16[0], a16[1], a16[2], a16[3], c16);
        h16b = h16;

        const long ob = orow + (long)t * D_INP;
#pragma unroll
        for (int r = 0; r < 4; ++r)
            out[ob + 4*G + r] = hval[r];
        if (G == 0)
            out[ob + 16] = h16;
    }
}

extern "C" void kernel_launch(void* const* d_in, const int* in_sizes, int n_in,
                              void* d_out, int out_size, void* d_ws, size_t ws_size,
                              hipStream_t stream) {
    (void)in_sizes; (void)n_in; (void)d_ws; (void)ws_size; (void)out_size;
    dim3 grid(B_TOT / 16);
    dim3 block(64);
    hipLaunchKernelGGL(lstm_ae_mfma11, grid, block, 0, stream,
        (const float*)d_in[0],
        (const float*)d_in[1],
        (const float*)d_in[2],
        (const float*)d_in[3],
        (const float*)d_in[4],
        (const float*)d_in[5],
        (const float*)d_in[6],
        (const float*)d_in[7],
        (const float*)d_in[8],
        (const float*)d_in[9],
        (const float*)d_in[10],
        (const float*)d_in[11],
        (const float*)d_in[12],
        (float*)d_out);
}